// Round 1
// baseline (71816.064 us; speedup 1.0000x reference)
//
#include <hip/hip_runtime.h>
#include <math.h>

// LSTM forward: T=1024 steps, B=64, I=256, H=512, gates 4H=2048. fp32.
// Baseline structure: one fused step-kernel launch per timestep (the launch
// is the grid-wide sync). h chains through d_out (it IS the output hs),
// c ping-pongs through d_ws.

#define T_STEPS 1024
#define BB      64
#define II      256
#define HH      512
#define G4H     2048
#define NC      2        // cells per block -> grid = H/NC = 256 blocks

__global__ __launch_bounds__(256) void lstm_step(
    const float* __restrict__ x,       // [T,B,I]
    int t,
    const float* __restrict__ h_prev,  // [B,H]
    const float* __restrict__ c_prev,  // [B,H]
    float*       __restrict__ c_out,   // [B,H]
    float*       __restrict__ h_out,   // [B,H] == d_out + t*B*H
    const float* __restrict__ Wi,      // [I,4H] row-major
    const float* __restrict__ Wh,      // [H,4H] row-major
    const float* __restrict__ bi,      // [4H]
    const float* __restrict__ bh)      // [4H]
{
    const int tid = threadIdx.x;
    const int g   = tid >> 6;      // wave id = gate id (0..3), wave-uniform
    const int b   = tid & 63;      // lane id = batch row
    const int j0  = blockIdx.x * NC;

    __shared__ float gl[4][NC][BB];

    const float* xrow = x + ((size_t)t * BB + b) * II;
    const float* hrow = h_prev + b * HH;

    #pragma unroll
    for (int cell = 0; cell < NC; ++cell) {
        // gate column index, uniform across the wave -> scalar weight stream
        const int col = __builtin_amdgcn_readfirstlane(g * HH + j0 + cell);
        float acc = bi[col] + bh[col];

        // x_t @ Wi contribution (K = 256)
        #pragma unroll 4
        for (int k = 0; k < II; k += 4) {
            const float4 xv = *(const float4*)(xrow + k);
            acc += xv.x * Wi[(size_t)(k + 0) * G4H + col];
            acc += xv.y * Wi[(size_t)(k + 1) * G4H + col];
            acc += xv.z * Wi[(size_t)(k + 2) * G4H + col];
            acc += xv.w * Wi[(size_t)(k + 3) * G4H + col];
        }
        // h_{t-1} @ Wh contribution (K = 512)
        #pragma unroll 4
        for (int k = 0; k < HH; k += 4) {
            const float4 hv = *(const float4*)(hrow + k);
            acc += hv.x * Wh[(size_t)(k + 0) * G4H + col];
            acc += hv.y * Wh[(size_t)(k + 1) * G4H + col];
            acc += hv.z * Wh[(size_t)(k + 2) * G4H + col];
            acc += hv.w * Wh[(size_t)(k + 3) * G4H + col];
        }
        gl[g][cell][b] = acc;
    }
    __syncthreads();

    // combine gates -> cell update (first NC*64 threads, one per (cell,b))
    if (tid < NC * BB) {
        const int cell = tid >> 6;
        const int bb   = tid & 63;
        const int j    = j0 + cell;

        float ig = gl[0][cell][bb];
        float fg = gl[1][cell][bb];
        float gg = gl[2][cell][bb];
        float og = gl[3][cell][bb];

        ig = 1.0f / (1.0f + __expf(-ig));
        fg = 1.0f / (1.0f + __expf(-fg));
        og = 1.0f / (1.0f + __expf(-og));
        gg = tanhf(gg);

        const float c  = c_prev[bb * HH + j];
        const float cn = fg * c + ig * gg;
        const float hn = og * tanhf(cn);

        c_out[bb * HH + j] = cn;
        h_out[bb * HH + j] = hn;
    }
}

extern "C" void kernel_launch(void* const* d_in, const int* in_sizes, int n_in,
                              void* d_out, int out_size, void* d_ws, size_t ws_size,
                              hipStream_t stream) {
    const float* x  = (const float*)d_in[0];
    const float* Wi = (const float*)d_in[1];
    const float* Wh = (const float*)d_in[2];
    const float* bi = (const float*)d_in[3];
    const float* bh = (const float*)d_in[4];
    const float* h0 = (const float*)d_in[5];
    const float* c0 = (const float*)d_in[6];
    float* out = (float*)d_out;

    float* cbuf0 = (float*)d_ws;             // [B,H]
    float* cbuf1 = cbuf0 + BB * HH;          // [B,H]

    for (int t = 0; t < T_STEPS; ++t) {
        const float* hp = (t == 0) ? h0 : out + (size_t)(t - 1) * BB * HH;
        const float* cp = (t == 0) ? c0 : ((t & 1) ? cbuf0 : cbuf1);
        float*       cn = (t & 1) ? cbuf1 : cbuf0;

        lstm_step<<<HH / NC, 256, 0, stream>>>(
            x, t, hp, cp, cn, out + (size_t)t * BB * HH, Wi, Wh, bi, bh);
    }
}

// Round 2
// 19332.997 us; speedup vs baseline: 3.7147x; 3.7147x over previous
//
#include <hip/hip_runtime.h>
#include <math.h>

// LSTM forward: T=1024, B=64, I=256, H=512 (4H=2048), fp32.
// One launch per timestep (launch = grid sync). Step kernel:
//   grid 256 = 32 cell-groups(16 cells) x 8 b-groups(8 rows), block 256.
//   lanes span (gate, cell) -> coalesced weight loads; h/x staged in LDS,
//   read as wave-uniform float4 broadcasts. Fused cell-update epilogue.
// c ping-pongs through d_ws; h chains through d_out (it IS the output).

#define T_STEPS 1024
#define BB      64
#define II      256
#define HH      512
#define G4H     2048

__global__ __launch_bounds__(256) void lstm_step(
    const float* __restrict__ x,       // [T,B,I]
    int t,
    const float* __restrict__ h_prev,  // [B,H]
    const float* __restrict__ c_prev,  // [B,H]
    float*       __restrict__ c_out,   // [B,H]
    float*       __restrict__ h_out,   // [B,H] == d_out + t*B*H
    const float* __restrict__ Wi,      // [I,4H] row-major
    const float* __restrict__ Wh,      // [H,4H] row-major
    const float* __restrict__ bi,      // [4H]
    const float* __restrict__ bh)      // [4H]
{
    const int tid = threadIdx.x;
    const int mg  = blockIdx.x & 31;   // cell-group: cells [mg*16, mg*16+16)
    const int bg  = blockIdx.x >> 5;   // batch-group: rows [bg*8, bg*8+8)

    __shared__ float hlds[8][HH];      // 16 KB
    __shared__ float xlds[8][II];      // 8 KB
    __shared__ float gl[4][16][8];     // gates: [gate][cell][b] 2 KB

    // ---- stage h (4096 floats) and x_t (2048 floats), coalesced ----
    {
        const float4* hsrc = (const float4*)(h_prev + (size_t)bg * 8 * HH);
        float4* hdst = (float4*)&hlds[0][0];
        #pragma unroll
        for (int i = 0; i < 4; ++i) hdst[tid + 256 * i] = hsrc[tid + 256 * i];

        const float4* xsrc = (const float4*)(x + ((size_t)t * BB + bg * 8) * II);
        float4* xdst = (float4*)&xlds[0][0];
        #pragma unroll
        for (int i = 0; i < 2; ++i) xdst[tid + 256 * i] = xsrc[tid + 256 * i];
    }
    __syncthreads();

    // ---- GEMM phase: thread = (gate g, cell m) x (b0,b1) ----
    const int lane = tid & 63;
    const int wave = tid >> 6;             // b-pair index 0..3
    const int g    = lane >> 4;            // gate 0..3
    const int m    = lane & 15;            // cell offset 0..15
    const int j    = g * HH + mg * 16 + m; // gate column 0..2047
    const int b0   = wave * 2;             // local batch rows
    const int b1   = b0 + 1;

    float acc0 = bi[j] + bh[j];
    float acc1 = acc0;

    const float4* h0v = (const float4*)&hlds[b0][0];
    const float4* h1v = (const float4*)&hlds[b1][0];
    const float*  wh  = Wh + j;

    #pragma unroll 4
    for (int k4 = 0; k4 < HH / 4; ++k4) {
        const float4 ha = h0v[k4];
        const float4 hb = h1v[k4];
        const float w0 = wh[(size_t)(4 * k4 + 0) * G4H];
        const float w1 = wh[(size_t)(4 * k4 + 1) * G4H];
        const float w2 = wh[(size_t)(4 * k4 + 2) * G4H];
        const float w3 = wh[(size_t)(4 * k4 + 3) * G4H];
        acc0 = fmaf(ha.x, w0, acc0); acc1 = fmaf(hb.x, w0, acc1);
        acc0 = fmaf(ha.y, w1, acc0); acc1 = fmaf(hb.y, w1, acc1);
        acc0 = fmaf(ha.z, w2, acc0); acc1 = fmaf(hb.z, w2, acc1);
        acc0 = fmaf(ha.w, w3, acc0); acc1 = fmaf(hb.w, w3, acc1);
    }

    const float4* x0v = (const float4*)&xlds[b0][0];
    const float4* x1v = (const float4*)&xlds[b1][0];
    const float*  wi  = Wi + j;

    #pragma unroll 4
    for (int k4 = 0; k4 < II / 4; ++k4) {
        const float4 xa = x0v[k4];
        const float4 xb = x1v[k4];
        const float w0 = wi[(size_t)(4 * k4 + 0) * G4H];
        const float w1 = wi[(size_t)(4 * k4 + 1) * G4H];
        const float w2 = wi[(size_t)(4 * k4 + 2) * G4H];
        const float w3 = wi[(size_t)(4 * k4 + 3) * G4H];
        acc0 = fmaf(xa.x, w0, acc0); acc1 = fmaf(xb.x, w0, acc1);
        acc0 = fmaf(xa.y, w1, acc0); acc1 = fmaf(xb.y, w1, acc1);
        acc0 = fmaf(xa.z, w2, acc0); acc1 = fmaf(xb.z, w2, acc1);
        acc0 = fmaf(xa.w, w3, acc0); acc1 = fmaf(xb.w, w3, acc1);
    }

    gl[g][m][b0] = acc0;
    gl[g][m][b1] = acc1;
    __syncthreads();

    // ---- fused cell update: 16 cells x 8 rows = 128 threads ----
    if (tid < 128) {
        const int bl = tid >> 4;           // local batch row 0..7
        const int mc = tid & 15;           // local cell 0..15

        float ig = gl[0][mc][bl];
        float fg = gl[1][mc][bl];
        float gg = gl[2][mc][bl];
        float og = gl[3][mc][bl];

        ig = 1.0f / (1.0f + __expf(-ig));
        fg = 1.0f / (1.0f + __expf(-fg));
        og = 1.0f / (1.0f + __expf(-og));
        gg = tanhf(gg);

        const size_t idx = (size_t)(bg * 8 + bl) * HH + mg * 16 + mc;
        const float c  = c_prev[idx];
        const float cn = fg * c + ig * gg;
        const float hn = og * tanhf(cn);

        c_out[idx] = cn;
        h_out[idx] = hn;
    }
}

extern "C" void kernel_launch(void* const* d_in, const int* in_sizes, int n_in,
                              void* d_out, int out_size, void* d_ws, size_t ws_size,
                              hipStream_t stream) {
    const float* x  = (const float*)d_in[0];
    const float* Wi = (const float*)d_in[1];
    const float* Wh = (const float*)d_in[2];
    const float* bi = (const float*)d_in[3];
    const float* bh = (const float*)d_in[4];
    const float* h0 = (const float*)d_in[5];
    const float* c0 = (const float*)d_in[6];
    float* out = (float*)d_out;

    float* cbuf0 = (float*)d_ws;            // [B,H]
    float* cbuf1 = cbuf0 + BB * HH;         // [B,H]

    for (int t = 0; t < T_STEPS; ++t) {
        const float* hp = (t == 0) ? h0 : out + (size_t)(t - 1) * BB * HH;
        const float* cp = (t == 0) ? c0 : ((t & 1) ? cbuf0 : cbuf1);
        float*       cn = (t & 1) ? cbuf1 : cbuf0;

        lstm_step<<<256, 256, 0, stream>>>(
            x, t, hp, cp, cn, out + (size_t)t * BB * HH, Wi, Wh, bi, bh);
    }
}

// Round 3
// 14247.935 us; speedup vs baseline: 5.0405x; 1.3569x over previous
//
#include <hip/hip_runtime.h>
#include <math.h>

// LSTM forward: T=1024, B=64, I=256, H=512 (4H=2048), fp32.
// Round 3: launch-per-step (launch = grid sync) but
//   * weights pre-packed ONCE into d_ws as per-block [8 col][768 k] slices
//   * step kernel: weights LDS-resident, read wave-uniform (broadcast ~free)
//   * activations (x_t, h) staged in LDS row-major pad-4 (balanced banks),
//     read per-lane (lane = batch row) as float4
//   * 3 K-passes (x, h-lo, h-hi) reuse one 66.5KB act buffer -> 91KB LDS
// c ping-pongs in d_ws; h chains through d_out.

#define T_STEPS 1024
#define BB      64
#define II      256
#define HH      512
#define G4H     2048
#define KTOT    768            // II + HH
#define WPB     (8 * KTOT)     // 6144 weights per block (8 cols x 768 k)

// d_ws layout (floats):
//   [0 .. 256*WPB)                     wpack   (6 MB)
//   [WOFF_B .. +256*8)                 bpack   (8 KB)
//   [COFF .. +2*B*H)                   c ping-pong (256 KB)
#define WOFF_B  (256 * WPB)
#define COFF    (WOFF_B + 256 * 8)
#define WS_NEEDED_BYTES ((size_t)(COFF + 2 * BB * HH) * 4)

// ---------------- one-time weight packing ----------------
__global__ __launch_bounds__(256) void pack_weights(
    const float* __restrict__ Wi, const float* __restrict__ Wh,
    const float* __restrict__ bi, const float* __restrict__ bh,
    float* __restrict__ wpack, float* __restrict__ bpack)
{
    const int blk = blockIdx.x;            // cells {2blk, 2blk+1}
    const int tid = threadIdx.x;
    #pragma unroll
    for (int i = 0; i < WPB / 256; ++i) {  // 24 iters, dst-coalesced
        const int f = tid + 256 * i;       // f = c*KTOT + k
        const int c = f / KTOT;            // 0..7  (c = g*2 + m)
        const int k = f - c * KTOT;
        const int j = (c >> 1) * HH + 2 * blk + (c & 1);
        const float w = (k < II) ? Wi[(size_t)k * G4H + j]
                                 : Wh[(size_t)(k - II) * G4H + j];
        wpack[(size_t)blk * WPB + f] = w;
    }
    if (tid < 8) {
        const int j = (tid >> 1) * HH + 2 * blk + (tid & 1);
        bpack[blk * 8 + tid] = bi[j] + bh[j];
    }
}

// ---------------- per-timestep kernel ----------------
// PACKED=true : stage weights from wpack (dense 24KB, coalesced)
// PACKED=false: stage weights straight from Wi/Wh (scattered; ws fallback)
template <bool PACKED>
__global__ __launch_bounds__(256) void lstm_step(
    const float* __restrict__ x_t,     // [64][256]
    const float* __restrict__ h_prev,  // [64][512]
    const float* __restrict__ c_prev,  // [64][512]
    float*       __restrict__ c_out,   // [64][512]
    float*       __restrict__ h_out,   // [64][512]
    const float* __restrict__ w_or_wi, // wpack | Wi
    const float* __restrict__ b_or_wh, // bpack | Wh
    const float* __restrict__ bi,      // only for !PACKED
    const float* __restrict__ bh)      // only for !PACKED
{
    __shared__ float wlds[WPB];        // [c][k], 24KB
    __shared__ float act[BB * 260];    // [r][260] (pad 4): 66.5KB
    __shared__ float gl[8 * BB];       // [c][r]
    __shared__ float bsh[8];

    const int tid = threadIdx.x;
    const int mg  = blockIdx.x;        // cells {2mg, 2mg+1}

    // ---- stage weights + bias into LDS ----
    if (PACKED) {
        const float4* src = (const float4*)(w_or_wi + (size_t)mg * WPB);
        float4* dst = (float4*)wlds;
        #pragma unroll
        for (int i = 0; i < 6; ++i) dst[tid + 256 * i] = src[tid + 256 * i];
        if (tid < 8) bsh[tid] = b_or_wh[mg * 8 + tid];
    } else {
        #pragma unroll
        for (int i = 0; i < WPB / 256; ++i) {
            const int f = tid + 256 * i;
            const int c = f / KTOT;
            const int k = f - c * KTOT;
            const int j = (c >> 1) * HH + 2 * mg + (c & 1);
            wlds[f] = (k < II) ? w_or_wi[(size_t)k * G4H + j]
                               : b_or_wh[(size_t)(k - II) * G4H + j];
        }
        if (tid < 8) {
            const int j = (tid >> 1) * HH + 2 * mg + (tid & 1);
            bsh[tid] = bi[j] + bh[j];
        }
    }

    const int r  = tid & 63;           // lane = batch row
    const int g  = tid >> 6;           // wave = gate
    const int c0 = 2 * g, c1 = 2 * g + 1;
    float acc0 = 0.f, acc1 = 0.f;

    const float4* actv = (const float4*)act;
    const float4* wv   = (const float4*)wlds;
    const int ab = r * 65;             // act row base (f4 units, stride 65)
    const int w0b = c0 * 192, w1b = c1 * 192;

    // ---- pass 0: x contribution (k = 0..255) ----
    {
        const float4* src = (const float4*)x_t;   // 4096 f4, coalesced
        float4* dstv = (float4*)act;
        #pragma unroll
        for (int i = 0; i < 16; ++i) {
            const int f  = tid + 256 * i;
            const int rr = f >> 6, k4 = f & 63;
            dstv[rr * 65 + k4] = src[f];
        }
        __syncthreads();
        #pragma unroll 4
        for (int k4 = 0; k4 < 64; ++k4) {
            const float4 a  = actv[ab + k4];
            const float4 w0 = wv[w0b + k4];
            const float4 w1 = wv[w1b + k4];
            acc0 += a.x * w0.x + a.y * w0.y + a.z * w0.z + a.w * w0.w;
            acc1 += a.x * w1.x + a.y * w1.y + a.z * w1.z + a.w * w1.w;
        }
    }

    // ---- passes 1,2: h contribution in two halves ----
    #pragma unroll
    for (int p = 0; p < 2; ++p) {
        __syncthreads();               // prev compute done before overwrite
        {
            const float4* src = (const float4*)h_prev;  // [64][128] f4
            float4* dstv = (float4*)act;
            #pragma unroll
            for (int i = 0; i < 16; ++i) {
                const int f  = tid + 256 * i;
                const int rr = f >> 6, k4 = f & 63;
                dstv[rr * 65 + k4] = src[rr * 128 + p * 64 + k4];
            }
        }
        __syncthreads();
        const int wb = 64 + p * 64;
        #pragma unroll 4
        for (int k4 = 0; k4 < 64; ++k4) {
            const float4 a  = actv[ab + k4];
            const float4 w0 = wv[w0b + wb + k4];
            const float4 w1 = wv[w1b + wb + k4];
            acc0 += a.x * w0.x + a.y * w0.y + a.z * w0.z + a.w * w0.w;
            acc1 += a.x * w1.x + a.y * w1.y + a.z * w1.z + a.w * w1.w;
        }
    }

    gl[c0 * 64 + r] = acc0;
    gl[c1 * 64 + r] = acc1;
    __syncthreads();

    // ---- fused cell update: 2 cells x 64 rows = 128 threads ----
    if (tid < 128) {
        const int m  = tid >> 6;       // local cell
        const int rr = tid & 63;       // batch row

        float ig = gl[(0 + m) * 64 + rr] + bsh[0 + m];
        float fg = gl[(2 + m) * 64 + rr] + bsh[2 + m];
        float gg = gl[(4 + m) * 64 + rr] + bsh[4 + m];
        float og = gl[(6 + m) * 64 + rr] + bsh[6 + m];

        ig = 1.0f / (1.0f + __expf(-ig));
        fg = 1.0f / (1.0f + __expf(-fg));
        og = 1.0f / (1.0f + __expf(-og));
        gg = tanhf(gg);

        const size_t idx = (size_t)rr * HH + 2 * mg + m;
        const float cv = c_prev[idx];
        const float cn = fg * cv + ig * gg;
        h_out[idx] = og * tanhf(cn);
        c_out[idx] = cn;
    }
}

extern "C" void kernel_launch(void* const* d_in, const int* in_sizes, int n_in,
                              void* d_out, int out_size, void* d_ws, size_t ws_size,
                              hipStream_t stream) {
    const float* x  = (const float*)d_in[0];
    const float* Wi = (const float*)d_in[1];
    const float* Wh = (const float*)d_in[2];
    const float* bi = (const float*)d_in[3];
    const float* bh = (const float*)d_in[4];
    const float* h0 = (const float*)d_in[5];
    const float* c0 = (const float*)d_in[6];
    float* out = (float*)d_out;
    float* ws  = (float*)d_ws;

    const bool packed = (ws_size >= WS_NEEDED_BYTES);

    float* wpack = ws;
    float* bpack = ws + WOFF_B;
    // c ping-pong: if ws too small for pack, still need 2*B*H floats at base
    float* cbase = packed ? (ws + COFF) : ws;
    float* cb[2] = { cbase, cbase + BB * HH };

    if (packed) {
        pack_weights<<<256, 256, 0, stream>>>(Wi, Wh, bi, bh, wpack, bpack);
    }

    for (int t = 0; t < T_STEPS; ++t) {
        const float* x_t = x + (size_t)t * BB * II;
        const float* hp  = (t == 0) ? h0 : out + (size_t)(t - 1) * BB * HH;
        const float* cp  = (t == 0) ? c0 : cb[1 - (t & 1)];
        float* cn        = cb[t & 1];
        float* hn        = out + (size_t)t * BB * HH;

        if (packed) {
            lstm_step<true><<<256, 256, 0, stream>>>(
                x_t, hp, cp, cn, hn, wpack, bpack, bi, bh);
        } else {
            lstm_step<false><<<256, 256, 0, stream>>>(
                x_t, hp, cp, cn, hn, Wi, Wh, bi, bh);
        }
    }
}